// Round 6
// baseline (1709.353 us; speedup 1.0000x reference)
//
#include <hip/hip_runtime.h>
#include <hip/hip_bf16.h>

// Problem constants (fixed by the reference)
#define BSZ  64
#define ILEN 256
#define TLEN 64
#define TTOT (ILEN + TLEN)   // 320
#define IDIM 512
#define HDIM 1024
#define ODIM 128

// Round 6: input projection hoisted out of the sequential loop (xproj GEMM,
// fp16 storage). Recurrent loop carries ONLY w_hh: 16 frags/wave = 64 VGPR
// (named vars + asm pin -> trivially resident; round 4/5's 24-frag array
// version never achieved residency, VGPR_Count=80). 256 blocks = 1/CU
// (deadlock-safe co-residency), 4 batch-groups x 16 rows, block owns 16
// units. h/flag traffic via relaxed SYSTEM-scope atomics (sc0 sc1 -> IF,
// coherent, fence-free). Fine-grained 8-producer polls, h ring depth 4.
#define NBLK 256
#define NTHR 512
#define GRP  4
#define GBLK 64          // blocks per group
#define UPB  16          // hidden units per block
#define NT   4           // n-tiles (16 gate rows each)
#define PQ   76          // LDS partial pitch (floats)
#define HSLOT (BSZ * HDIM)

typedef __attribute__((ext_vector_type(8))) short short8;  // 8 x bf16
typedef __attribute__((ext_vector_type(4))) float f32x4;
typedef _Float16 half_t;

__device__ inline ushort f2bf(float f) {            // RNE float->bf16
  unsigned u = __builtin_bit_cast(unsigned, f);
  u += 0x7fffu + ((u >> 16) & 1u);
  return (ushort)(u >> 16);
}

__device__ inline float fast_sigmoid(float x) {
  float e = __expf(-x);
  return 1.0f / (1.0f + e);
}
__device__ inline float fast_tanh(float x) {
  float e = __expf(2.0f * x);
  return 1.0f - 2.0f / (1.0f + e);
}

// ---- IF-coherent ops (compiler-known: waitcnts auto-inserted) ----
__device__ inline short8 ld_h16(const ushort* p) {   // 16B via 2x8B system loads
  unsigned long lo = __hip_atomic_load((const unsigned long*)p,
                                       __ATOMIC_RELAXED, __HIP_MEMORY_SCOPE_SYSTEM);
  unsigned long hi = __hip_atomic_load((const unsigned long*)(p + 4),
                                       __ATOMIC_RELAXED, __HIP_MEMORY_SCOPE_SYSTEM);
  union { unsigned long u[2]; short8 v; } c;
  c.u[0] = lo; c.u[1] = hi;
  return c.v;
}
__device__ inline void st_h(ushort* p, ushort v) {
  __hip_atomic_store(p, v, __ATOMIC_RELAXED, __HIP_MEMORY_SCOPE_SYSTEM);
}
__device__ inline int ld_flag(const int* p) {
  return __hip_atomic_load(p, __ATOMIC_RELAXED, __HIP_MEMORY_SCOPE_SYSTEM);
}
__device__ inline void st_flag(int* p, int v) {
  __hip_atomic_store(p, v, __ATOMIC_RELAXED, __HIP_MEMORY_SCOPE_SYSTEM);
}
__device__ inline void vm_drain() { asm volatile("s_waitcnt vmcnt(0)" ::: "memory"); }

// ---------------- prep: bf16 conversions, w_hh swizzle, zero h0/flags ----------------
// whh_sw fragment index f = (((gb*8 + wv)*4 + c)*4 + nt)*64 + lane; 8 bf16 each.
__global__ void prep_kernel(const float* __restrict__ inp, const float* __restrict__ clfw,
                            const float* __restrict__ w_ih, const float* __restrict__ w_hh,
                            ushort* __restrict__ inp_bf, ushort* __restrict__ clfw_bf,
                            ushort* __restrict__ wih_bf, ushort* __restrict__ whh_sw,
                            ushort* __restrict__ hbuf, int* __restrict__ bar)
{
  const long np  = (long)gridDim.x * blockDim.x;
  const long tid = (long)blockIdx.x * blockDim.x + threadIdx.x;

  const float4* in4 = (const float4*)inp;
  ushort4* ob4 = (ushort4*)inp_bf;
  for (long i = tid; i < (long)BSZ * ILEN * IDIM / 4; i += np) {
    float4 v = in4[i];
    ushort4 o; o.x = f2bf(v.x); o.y = f2bf(v.y); o.z = f2bf(v.z); o.w = f2bf(v.w);
    ob4[i] = o;
  }
  const float4* cw4 = (const float4*)clfw;
  ushort4* cb4 = (ushort4*)clfw_bf;
  for (long i = tid; i < (long)ODIM * HDIM / 4; i += np) {
    float4 v = cw4[i];
    ushort4 o; o.x = f2bf(v.x); o.y = f2bf(v.y); o.z = f2bf(v.z); o.w = f2bf(v.w);
    cb4[i] = o;
  }
  const float4* wi4 = (const float4*)w_ih;
  ushort4* wb4 = (ushort4*)wih_bf;
  for (long i = tid; i < (long)4 * HDIM * IDIM / 4; i += np) {
    float4 v = wi4[i];
    ushort4 o; o.x = f2bf(v.x); o.y = f2bf(v.y); o.z = f2bf(v.z); o.w = f2bf(v.w);
    wb4[i] = o;
  }
  // w_hh swizzle: 64gb x 8wv x 4c x 4nt x 64lane fragments of 8
  for (long f = tid; f < 64L * 8 * 4 * 4 * 64; f += np) {   // 524288
    const int lane = (int)(f & 63);
    const int nt   = (int)((f >> 6) & 3);
    const int c    = (int)((f >> 8) & 3);
    const int wv   = (int)((f >> 10) & 7);
    const int gb   = (int)(f >> 13);
    const int nl   = nt * 16 + (lane & 15);
    const long grow = (long)(nl >> 4) * HDIM + gb * UPB + (nl & 15);
    const int k = wv * 32 + c * 256 + (lane >> 4) * 8;
    const float* src = w_hh + grow * HDIM + k;
    ushort* dst = whh_sw + f * 8;
    #pragma unroll
    for (int j = 0; j < 8; ++j) dst[j] = f2bf(src[j]);
  }
  // zero all 4 h ring slots through the SAME (system/IF) path readers use
  for (long i = tid; i < (long)4 * HSLOT; i += np)
    st_h(hbuf + i, 0);
  for (long i = tid; i < NBLK * 32; i += np) st_flag(bar + (int)i, 0);
}

// ---------------- xproj GEMM: xp[m=b*ILEN+t][n] = inp[m] . w_ih[n] ----------------
// M=16384, N=4096, K=512. Block = 128x64 tile, 4 waves stacked in M.
__global__ __launch_bounds__(256, 1) void xproj_kernel(
    const ushort* __restrict__ inp_bf, const ushort* __restrict__ wih_bf,
    half_t* __restrict__ xproj)
{
  const int tid = threadIdx.x;
  const int wv = tid >> 6, lane = tid & 63, l15 = lane & 15, quad = lane >> 4;
  const int mtile = blockIdx.x >> 6;      // 0..127
  const int ntile = blockIdx.x & 63;      // 0..63
  const int mb = mtile * 128 + wv * 32;   // wave's 32 rows
  const int nb = ntile * 64;

  f32x4 acc[2][NT];
  #pragma unroll
  for (int mi = 0; mi < 2; ++mi)
    #pragma unroll
    for (int nt = 0; nt < NT; ++nt)
      #pragma unroll
      for (int r = 0; r < 4; ++r) acc[mi][nt][r] = 0.0f;

  for (int kc = 0; kc < IDIM / 32; ++kc) {
    const int k = kc * 32 + quad * 8;
    short8 a0 = *(const short8*)(inp_bf + (long)(mb + l15) * IDIM + k);
    short8 a1 = *(const short8*)(inp_bf + (long)(mb + 16 + l15) * IDIM + k);
    #pragma unroll
    for (int nt = 0; nt < NT; ++nt) {
      short8 b = *(const short8*)(wih_bf + (long)(nb + nt * 16 + l15) * IDIM + k);
      acc[0][nt] = __builtin_amdgcn_mfma_f32_16x16x32_bf16(a0, b, acc[0][nt], 0, 0, 0);
      acc[1][nt] = __builtin_amdgcn_mfma_f32_16x16x32_bf16(a1, b, acc[1][nt], 0, 0, 0);
    }
  }
  #pragma unroll
  for (int mi = 0; mi < 2; ++mi)
    #pragma unroll
    for (int nt = 0; nt < NT; ++nt)
      #pragma unroll
      for (int r = 0; r < 4; ++r) {
        const int m = mb + mi * 16 + quad * 4 + r;
        xproj[(long)m * (4 * HDIM) + nb + nt * 16 + l15] = (half_t)acc[mi][nt][r];
      }
}

// ---------------- persistent LSTM kernel ----------------
// MFMA 16x16x32 bf16 layouts (validated rounds 1-5):
//   A frag: A[m = lane&15][k = (lane>>4)*8 + j]
//   B frag: rows W[n][k], n = lane&15, k = (lane>>4)*8 + j
//   C/D:    col(n) = lane&15, row(m) = (lane>>4)*4 + reg
#define MFMA4(afrag, c) do {                                                            \
  acc[0] = __builtin_amdgcn_mfma_f32_16x16x32_bf16(afrag, w##c##0, acc[0], 0, 0, 0);    \
  acc[1] = __builtin_amdgcn_mfma_f32_16x16x32_bf16(afrag, w##c##1, acc[1], 0, 0, 0);    \
  acc[2] = __builtin_amdgcn_mfma_f32_16x16x32_bf16(afrag, w##c##2, acc[2], 0, 0, 0);    \
  acc[3] = __builtin_amdgcn_mfma_f32_16x16x32_bf16(afrag, w##c##3, acc[3], 0, 0, 0);    \
} while (0)

__global__ __launch_bounds__(NTHR, 2) void lstm_kernel(
    const ushort* __restrict__ whh_sw, const half_t* __restrict__ xproj,
    const float* __restrict__ bias,
    ushort* __restrict__ hbuf, ushort* __restrict__ hs_bf,
    int* __restrict__ flags)
{
  extern __shared__ float part[];   // [8 waves][16 m][PQ]

  const int tid  = threadIdx.x;
  const int wv   = tid >> 6;        // wave 0..7 (K=1024 split 8 ways)
  const int lane = tid & 63;
  const int l15  = lane & 15;
  const int quad = lane >> 4;
  const int blk  = blockIdx.x;
  const int g    = blk >> 6;        // batch group 0..3
  const int gb   = blk & 63;        // block within group
  const int j0u  = gb * UPB;        // first hidden unit owned by this block
  const int m0   = g * 16;          // first batch row of this group

  // ---- 16 named register-resident bf16 w_hh fragments (64 VGPR) ----
  const ushort* wp = whh_sw + ((long)(gb * 8 + wv) * 16 * 64 + lane) * 8;
  short8 w00 = *(const short8*)(wp + 0  * 512);
  short8 w01 = *(const short8*)(wp + 1  * 512);
  short8 w02 = *(const short8*)(wp + 2  * 512);
  short8 w03 = *(const short8*)(wp + 3  * 512);
  short8 w10 = *(const short8*)(wp + 4  * 512);
  short8 w11 = *(const short8*)(wp + 5  * 512);
  short8 w12 = *(const short8*)(wp + 6  * 512);
  short8 w13 = *(const short8*)(wp + 7  * 512);
  short8 w20 = *(const short8*)(wp + 8  * 512);
  short8 w21 = *(const short8*)(wp + 9  * 512);
  short8 w22 = *(const short8*)(wp + 10 * 512);
  short8 w23 = *(const short8*)(wp + 11 * 512);
  short8 w30 = *(const short8*)(wp + 12 * 512);
  short8 w31 = *(const short8*)(wp + 13 * 512);
  short8 w32 = *(const short8*)(wp + 14 * 512);
  short8 w33 = *(const short8*)(wp + 15 * 512);
  asm volatile("" : "+v"(w00), "+v"(w01), "+v"(w02), "+v"(w03),
                    "+v"(w10), "+v"(w11), "+v"(w12), "+v"(w13));
  asm volatile("" : "+v"(w20), "+v"(w21), "+v"(w22), "+v"(w23),
                    "+v"(w30), "+v"(w31), "+v"(w32), "+v"(w33));

  // ---- elementwise cell mapping: threads 0..255 own (batch em, unit uu) ----
  const int em = tid >> 4;          // 0..15 (valid when tid<256)
  const int uu = tid & 15;          // 0..15
  float bi = 0, bf_ = 0, bg = 0, bo = 0;
  const half_t* xgp = xproj + (long)(m0 + em) * ILEN * (4 * HDIM) + j0u + uu;
  if (tid < 256) {
    bi  = bias[0 * HDIM + j0u + uu];
    bf_ = bias[1 * HDIM + j0u + uu];
    bg  = bias[2 * HDIM + j0u + uu];
    bo  = bias[3 * HDIM + j0u + uu];
  }
  float cst = 0.0f;

  // ---- fine-grained sync: wave wv chunk c produced by blocks 2wv+16c, +1 ----
  int* const fmine = flags + blk * 32;        // own flag (128B stride)
  const int prodgb = 2 * wv + 16 * ((lane >> 1) & 3) + (lane & 1);
  const int fidx   = (lane < 8) ? (g * GBLK + prodgb) : blk;
  const int* const myfp = flags + fidx * 32;

  // prefetch x gates for t=0 (plain cached loads, fp16)
  float xi = 0, xf = 0, xg = 0, xo = 0;
  if (tid < 256) {
    xi = (float)xgp[0 * HDIM]; xf = (float)xgp[1 * HDIM];
    xg = (float)xgp[2 * HDIM]; xo = (float)xgp[3 * HDIM];
  }

  for (int t = 0; t < TTOT; ++t) {
    const ushort* __restrict__ hsrc = hbuf + (t & 3) * HSLOT;
    ushort* __restrict__ hdst = hbuf + ((t + 1) & 3) * HSLOT;

    // ---- wave-level poll: h_t ready when this wave's 8 producers flag >= t ----
    for (;;) {
      int v = ld_flag(myfp);
      if (__all(v >= t)) break;
    }

    // ---- h loads via IF for this wave's K slice ----
    const ushort* hb = hsrc + (long)(m0 + l15) * HDIM + wv * 32 + quad * 8;
    short8 ah0 = ld_h16(hb);
    short8 ah1 = ld_h16(hb + 256);
    short8 ah2 = ld_h16(hb + 512);
    short8 ah3 = ld_h16(hb + 768);

    f32x4 acc[NT];
    #pragma unroll
    for (int nt = 0; nt < NT; ++nt)
      #pragma unroll
      for (int r = 0; r < 4; ++r) acc[nt][r] = 0.0f;

    MFMA4(ah0, 0);
    MFMA4(ah1, 1);
    MFMA4(ah2, 2);
    MFMA4(ah3, 3);

    // ---- partials to LDS, [w][m][n] (writes 2-way = free at PQ=76) ----
    #pragma unroll
    for (int nt = 0; nt < NT; ++nt)
      #pragma unroll
      for (int r = 0; r < 4; ++r)
        part[(wv * 16 + quad * 4 + r) * PQ + nt * 16 + l15] = acc[nt][r];
    __syncthreads();    // all waves passed polls => all 64 group flags >= t
                        // => ring slot (t+1)&3 (holding h(t-3)) safe to overwrite

    // ---- reduce 8 partials, LSTM cell (threads 0..255) ----
    ushort h16 = 0;
    if (tid < 256) {
      float gi = bi + xi, gf = bf_ + xf, gg = bg + xg, go = bo + xo;
      #pragma unroll
      for (int w = 0; w < 8; ++w) {
        const float* pw = part + (w * 16 + em) * PQ;
        gi += pw[0 * 16 + uu];
        gf += pw[1 * 16 + uu];
        gg += pw[2 * 16 + uu];
        go += pw[3 * 16 + uu];
      }
      const float si = fast_sigmoid(gi);
      const float sf = fast_sigmoid(gf);
      const float tg = fast_tanh(gg);
      const float so = fast_sigmoid(go);
      cst = sf * cst + si * tg;
      const float h = so * fast_tanh(cst);
      h16 = f2bf(h);
      st_h(hdst + (long)(m0 + em) * HDIM + j0u + uu, h16);   // through IF
    }

    // ---- publish: own h stores at IF before flag store ----
    vm_drain();                              // per-thread store drain
    __syncthreads();                         // all threads drained; LDS reusable
    if (tid == 0) st_flag(fmine, t + 1);     // monotonic, no ABA

    // ---- off-critical-path work after publish ----
    if (tid < 256) {
      if (t >= ILEN)
        hs_bf[((long)(m0 + em) * TLEN + (t - ILEN)) * HDIM + j0u + uu] = h16;
      if (t + 1 < ILEN) {                    // prefetch x gates for t+1
        const half_t* xq = xgp + (long)(t + 1) * (4 * HDIM);
        xi = (float)xq[0 * HDIM]; xf = (float)xq[1 * HDIM];
        xg = (float)xq[2 * HDIM]; xo = (float)xq[3 * HDIM];
      } else {
        xi = xf = xg = xo = 0.0f;            // padded steps: bias only
      }
    }
  }
}

// ---------------- classifier: sigmoid(hs @ clf_w^T + clf_b) ----------------
__global__ __launch_bounds__(256, 1) void clf_kernel(
    const ushort* __restrict__ hs_bf, const ushort* __restrict__ clfw_bf,
    const float* __restrict__ clf_b, float* __restrict__ out)
{
  const int tid = threadIdx.x;
  const int wv = tid >> 6, lane = tid & 63, l15 = lane & 15, quad = lane >> 4;
  const int m0 = blockIdx.x * 64 + wv * 16;   // rows = (b, tt) pairs, 4096 total

  f32x4 acc[8];
  #pragma unroll
  for (int nt = 0; nt < 8; ++nt)
    #pragma unroll
    for (int r = 0; r < 4; ++r) acc[nt][r] = 0.0f;

  for (int kc = 0; kc < HDIM / 32; ++kc) {
    const int k = kc * 32 + quad * 8;
    short8 a = *(const short8*)(hs_bf + (long)(m0 + l15) * HDIM + k);
    #pragma unroll
    for (int nt = 0; nt < 8; ++nt) {
      short8 b = *(const short8*)(clfw_bf + (long)(nt * 16 + l15) * HDIM + k);
      acc[nt] = __builtin_amdgcn_mfma_f32_16x16x32_bf16(a, b, acc[nt], 0, 0, 0);
    }
  }
  #pragma unroll
  for (int nt = 0; nt < 8; ++nt) {
    const int n = nt * 16 + l15;
    const float bn = clf_b[n];
    #pragma unroll
    for (int r = 0; r < 4; ++r) {
      const int m = m0 + quad * 4 + r;
      out[(long)m * ODIM + n] = fast_sigmoid(acc[nt][r] + bn);
    }
  }
}

// ---------------- launch ----------------
extern "C" void kernel_launch(void* const* d_in, const int* in_sizes, int n_in,
                              void* d_out, int out_size, void* d_ws, size_t ws_size,
                              hipStream_t stream) {
  const float* inp   = (const float*)d_in[0];
  // d_in[1] = tlen scalar (fixed = 64 for this problem)
  const float* w_ih  = (const float*)d_in[2];
  const float* w_hh  = (const float*)d_in[3];
  const float* bias  = (const float*)d_in[4];
  const float* clf_w = (const float*)d_in[5];
  const float* clf_b = (const float*)d_in[6];
  float* out = (float*)d_out;

  // ws layout (bytes): total ~172.8 MB
  char* ws = (char*)d_ws;
  ushort* inp_bf  = (ushort*)(ws + 0);          // 16,777,216
  ushort* wih_bf  = (ushort*)(ws + 16777216);   //  4,194,304
  ushort* whh_sw  = (ushort*)(ws + 20971520);   //  8,388,608 (swizzled w_hh)
  ushort* clfw_bf = (ushort*)(ws + 29360128);   //    262,144
  ushort* hbuf    = (ushort*)(ws + 29622272);   //    524,288 (4-slot h ring)
  ushort* hs_bf   = (ushort*)(ws + 30146560);   //  8,388,608 (last-64-step h)
  int*    bar     = (int*)   (ws + 38535168);   //     32,768 (per-block flags)
  half_t* xproj   = (half_t*)(ws + 38567936);   // 134,217,728 (fp16 x-projection)

  prep_kernel<<<4096, 256, 0, stream>>>(inp, clf_w, w_ih, w_hh,
                                        inp_bf, clfw_bf, wih_bf, whh_sw, hbuf, bar);
  xproj_kernel<<<8192, 256, 0, stream>>>(inp_bf, wih_bf, xproj);
  lstm_kernel<<<NBLK, NTHR, 8 * 16 * PQ * 4, stream>>>(whh_sw, xproj, bias,
                                                       hbuf, hs_bf, bar);
  clf_kernel<<<64, 256, 0, stream>>>(hs_bf, clfw_bf, clf_b, out);
}

// Round 7
// 1326.532 us; speedup vs baseline: 1.2886x; 1.2886x over previous
//
#include <hip/hip_runtime.h>
#include <hip/hip_bf16.h>

// Problem constants (fixed by the reference)
#define BSZ  64
#define ILEN 256
#define TLEN 64
#define TTOT (ILEN + TLEN)   // 320
#define IDIM 512
#define HDIM 1024
#define ODIM 128

// Round 7: 8 batch-groups x 8 rows x 32 blocks (= 8 XCDs x 32 CUs under
// round-robin dispatch; group = blockIdx&7). A group is a CLOSED system
// (its h is produced/consumed only by its own blocks), so if all 32 blocks
// share one XCD (runtime-verified via HW_REG_XCC_ID census), h/flag traffic
// uses XCD-local L2 (plain stores + sc0 loads, RT ~80ns) instead of the
// Infinity-Cache sc0+sc1 path (RT ~250-600ns). Impure groups fall back to
// the proven round-6 IF path -- correctness never assumes placement (G16).
// Block owns 32 units (128 gate rows, NT=8); 8 waves K-split (128 K each);
// weights 32 frags/wave (128 regs, AGPR-resident per round-6 finding).
#define NBLK 256
#define NTHR 512
#define NGRP 8
#define GBLK 32          // blocks per group
#define UPB  32          // hidden units per block
#define NT   8           // n-tiles (16 gate rows each)
#define PN   132         // LDS partial pitch (floats)
#define HSLOT (BSZ * HDIM)

typedef __attribute__((ext_vector_type(8))) short short8;  // 8 x bf16
typedef __attribute__((ext_vector_type(4))) float f32x4;
typedef _Float16 half_t;

__device__ inline ushort f2bf(float f) {            // RNE float->bf16
  unsigned u = __builtin_bit_cast(unsigned, f);
  u += 0x7fffu + ((u >> 16) & 1u);
  return (ushort)(u >> 16);
}

__device__ inline float fast_sigmoid(float x) {
  float e = __expf(-x);
  return 1.0f / (1.0f + e);
}
__device__ inline float fast_tanh(float x) {
  float e = __expf(2.0f * x);
  return 1.0f - 2.0f / (1.0f + e);
}

__device__ inline void st_h_sys(ushort* p, ushort v) {   // IF path h store
  __hip_atomic_store(p, v, __ATOMIC_RELAXED, __HIP_MEMORY_SCOPE_SYSTEM);
}
__device__ inline void vm_drain() { asm volatile("s_waitcnt vmcnt(0)" ::: "memory"); }

template<bool FAST>
__device__ __forceinline__ int ldflag(const int* p) {
  if constexpr (FAST)
    return __hip_atomic_load(p, __ATOMIC_RELAXED, __HIP_MEMORY_SCOPE_AGENT);
  else
    return __hip_atomic_load(p, __ATOMIC_RELAXED, __HIP_MEMORY_SCOPE_SYSTEM);
}
template<bool FAST>
__device__ __forceinline__ void stflag(int* p, int v) {
  if constexpr (FAST)
    __hip_atomic_store(p, v, __ATOMIC_RELAXED, __HIP_MEMORY_SCOPE_AGENT);
  else
    __hip_atomic_store(p, v, __ATOMIC_RELAXED, __HIP_MEMORY_SCOPE_SYSTEM);
}

// 4x16B h loads with IN-ASM waitcnt: outputs are valid when the asm block
// ends, so consumer MFMAs carry a true data dependence (fixes round-3 race).
template<bool FAST>
__device__ __forceinline__ void ld_h4(const ushort* p, short8& a0, short8& a1,
                                      short8& a2, short8& a3) {
  if constexpr (FAST)
    asm volatile("global_load_dwordx4 %0, %4, off sc0\n\t"
                 "global_load_dwordx4 %1, %4, off offset:64 sc0\n\t"
                 "global_load_dwordx4 %2, %4, off offset:128 sc0\n\t"
                 "global_load_dwordx4 %3, %4, off offset:192 sc0\n\t"
                 "s_waitcnt vmcnt(0)"
                 : "=&v"(a0), "=&v"(a1), "=&v"(a2), "=&v"(a3)
                 : "v"(p) : "memory");
  else
    asm volatile("global_load_dwordx4 %0, %4, off sc0 sc1\n\t"
                 "global_load_dwordx4 %1, %4, off offset:64 sc0 sc1\n\t"
                 "global_load_dwordx4 %2, %4, off offset:128 sc0 sc1\n\t"
                 "global_load_dwordx4 %3, %4, off offset:192 sc0 sc1\n\t"
                 "s_waitcnt vmcnt(0)"
                 : "=&v"(a0), "=&v"(a1), "=&v"(a2), "=&v"(a3)
                 : "v"(p) : "memory");
}

// ---------------- prep: bf16 conversions, w_hh swizzle, zero state ----------------
// whh_sw frag index f = (((role*8 + wv)*4 + c)*8 + nt)*64 + lane; 8 bf16 each.
__global__ void prep_kernel(const float* __restrict__ inp, const float* __restrict__ clfw,
                            const float* __restrict__ w_ih, const float* __restrict__ w_hh,
                            ushort* __restrict__ inp_bf, ushort* __restrict__ clfw_bf,
                            ushort* __restrict__ wih_bf, ushort* __restrict__ whh_sw,
                            ushort* __restrict__ hbuf, int* __restrict__ bar,
                            int* __restrict__ hand)
{
  const long np  = (long)gridDim.x * blockDim.x;
  const long tid = (long)blockIdx.x * blockDim.x + threadIdx.x;

  const float4* in4 = (const float4*)inp;
  ushort4* ob4 = (ushort4*)inp_bf;
  for (long i = tid; i < (long)BSZ * ILEN * IDIM / 4; i += np) {
    float4 v = in4[i];
    ushort4 o; o.x = f2bf(v.x); o.y = f2bf(v.y); o.z = f2bf(v.z); o.w = f2bf(v.w);
    ob4[i] = o;
  }
  const float4* cw4 = (const float4*)clfw;
  ushort4* cb4 = (ushort4*)clfw_bf;
  for (long i = tid; i < (long)ODIM * HDIM / 4; i += np) {
    float4 v = cw4[i];
    ushort4 o; o.x = f2bf(v.x); o.y = f2bf(v.y); o.z = f2bf(v.z); o.w = f2bf(v.w);
    cb4[i] = o;
  }
  const float4* wi4 = (const float4*)w_ih;
  ushort4* wb4 = (ushort4*)wih_bf;
  for (long i = tid; i < (long)4 * HDIM * IDIM / 4; i += np) {
    float4 v = wi4[i];
    ushort4 o; o.x = f2bf(v.x); o.y = f2bf(v.y); o.z = f2bf(v.z); o.w = f2bf(v.w);
    wb4[i] = o;
  }
  // w_hh swizzle: 32role x 8wv x 4c x 8nt x 64lane fragments of 8
  for (long f = tid; f < 32L * 8 * 4 * 8 * 64; f += np) {   // 524288
    const int lane = (int)(f & 63);
    const int nt   = (int)((f >> 6) & 7);
    const int c    = (int)((f >> 9) & 3);
    const int wv   = (int)((f >> 11) & 7);
    const int r    = (int)(f >> 14);                // role 0..31
    const int nl   = nt * 16 + (lane & 15);         // 0..127
    const long grow = (long)(nl >> 5) * HDIM + r * UPB + (nl & 31);
    const int k = wv * 128 + c * 32 + (lane >> 4) * 8;
    const float* src = w_hh + grow * HDIM + k;
    ushort* dst = whh_sw + f * 8;
    #pragma unroll
    for (int j = 0; j < 8; ++j) dst[j] = f2bf(src[j]);
  }
  // zero h ring via the system path (memory-side => visible to both modes)
  for (long i = tid; i < (long)4 * HSLOT; i += np)
    st_h_sys(hbuf + i, 0);
  for (long i = tid; i < NBLK * 32; i += np)
    __hip_atomic_store(bar + (int)i, 0, __ATOMIC_RELAXED, __HIP_MEMORY_SCOPE_SYSTEM);
  for (long i = tid; i < 256; i += np)
    __hip_atomic_store(hand + (int)i, 0, __ATOMIC_RELAXED, __HIP_MEMORY_SCOPE_SYSTEM);
}

// ---------------- xproj GEMM: xp[m=b*ILEN+t][n] = inp[m] . w_ih[n] ----------------
__global__ __launch_bounds__(256, 1) void xproj_kernel(
    const ushort* __restrict__ inp_bf, const ushort* __restrict__ wih_bf,
    half_t* __restrict__ xproj)
{
  const int tid = threadIdx.x;
  const int wv = tid >> 6, lane = tid & 63, l15 = lane & 15, quad = lane >> 4;
  const int mtile = blockIdx.x >> 6;      // 0..127
  const int ntile = blockIdx.x & 63;      // 0..63
  const int mb = mtile * 128 + wv * 32;   // wave's 32 rows
  const int nb = ntile * 64;

  f32x4 acc[2][4];
  #pragma unroll
  for (int mi = 0; mi < 2; ++mi)
    #pragma unroll
    for (int nt = 0; nt < 4; ++nt)
      #pragma unroll
      for (int r = 0; r < 4; ++r) acc[mi][nt][r] = 0.0f;

  for (int kc = 0; kc < IDIM / 32; ++kc) {
    const int k = kc * 32 + quad * 8;
    short8 a0 = *(const short8*)(inp_bf + (long)(mb + l15) * IDIM + k);
    short8 a1 = *(const short8*)(inp_bf + (long)(mb + 16 + l15) * IDIM + k);
    #pragma unroll
    for (int nt = 0; nt < 4; ++nt) {
      short8 b = *(const short8*)(wih_bf + (long)(nb + nt * 16 + l15) * IDIM + k);
      acc[0][nt] = __builtin_amdgcn_mfma_f32_16x16x32_bf16(a0, b, acc[0][nt], 0, 0, 0);
      acc[1][nt] = __builtin_amdgcn_mfma_f32_16x16x32_bf16(a1, b, acc[1][nt], 0, 0, 0);
    }
  }
  #pragma unroll
  for (int mi = 0; mi < 2; ++mi)
    #pragma unroll
    for (int nt = 0; nt < 4; ++nt)
      #pragma unroll
      for (int r = 0; r < 4; ++r) {
        const int m = mb + mi * 16 + quad * 4 + r;
        xproj[(long)m * (4 * HDIM) + nb + nt * 16 + l15] = (half_t)acc[mi][nt][r];
      }
}

// ---------------- persistent LSTM body (templated on sync path) ----------------
// MFMA 16x16x32 bf16 layouts (validated rounds 1-6):
//   A frag: A[m = lane&15][k = (lane>>4)*8 + j]
//   B frag: rows W[n][k], n = lane&15, k = (lane>>4)*8 + j
//   C/D:    col(n) = lane&15, row(m) = (lane>>4)*4 + reg
template<bool FAST>
__device__ __forceinline__ void lstm_body(
    const ushort* __restrict__ whh_sw, const half_t* __restrict__ xproj,
    const float* __restrict__ bias, ushort* __restrict__ hbuf,
    ushort* __restrict__ hs_bf, int* __restrict__ flags)
{
  extern __shared__ float part[];   // [8 waves][16 m][PN] (67.6 KB)

  const int tid  = threadIdx.x;
  const int wv   = tid >> 6;        // wave 0..7 (K=1024 split 8 ways)
  const int lane = tid & 63;
  const int l15  = lane & 15;
  const int quad = lane >> 4;
  const int blk  = blockIdx.x;
  const int g    = blk & 7;         // batch group (likely XCD)
  const int role = blk >> 3;        // 0..31 within group
  const int j0u  = role * UPB;      // first hidden unit owned
  const int m0   = g * 8;           // first batch row of this group

  // ---- 32 weight fragments per wave (128 regs; AGPR-resident) ----
  short8 wfrag[4][NT];
  {
    const ushort* wp = whh_sw + (long)(role * 8 + wv) * 16384 + lane * 8;
    #pragma unroll
    for (int c = 0; c < 4; ++c)
      #pragma unroll
      for (int nt = 0; nt < NT; ++nt)
        wfrag[c][nt] = *(const short8*)(wp + (c * NT + nt) * 512);
  }
  #pragma unroll
  for (int c = 0; c < 4; ++c)
    #pragma unroll
    for (int nt = 0; nt < NT; ++nt)
      asm volatile("" : "+v"(wfrag[c][nt]));

  // ---- cell mapping: threads 0..255 own (batch em 0..7, unit uu 0..31) ----
  const int em = tid >> 5;
  const int uu = tid & 31;
  float bi = 0, bf_ = 0, bg = 0, bo = 0;
  const half_t* xgp = xproj + (long)(m0 + em) * ILEN * (4 * HDIM) + j0u + uu;
  if (tid < 256) {
    bi  = bias[0 * HDIM + j0u + uu];
    bf_ = bias[1 * HDIM + j0u + uu];
    bg  = bias[2 * HDIM + j0u + uu];
    bo  = bias[3 * HDIM + j0u + uu];
  }
  float cst = 0.0f;

  // ---- sync: wave wv's chunk c comes from role 4*wv + c ----
  int* const fmine = flags + (g * GBLK + role) * 32;
  const int fidx = (lane < 4) ? (g * GBLK + wv * 4 + lane) : (g * GBLK + role);
  const int* const myfp = flags + fidx * 32;

  // prefetch x gates for t=0 (plain cached fp16 loads; read-only data)
  float xi = 0, xf = 0, xg = 0, xo = 0;
  if (tid < 256) {
    xi = (float)xgp[0 * HDIM]; xf = (float)xgp[1 * HDIM];
    xg = (float)xgp[2 * HDIM]; xo = (float)xgp[3 * HDIM];
  }

  for (int t = 0; t < TTOT; ++t) {
    const ushort* __restrict__ hsrc = hbuf + (t & 3) * HSLOT;
    ushort* __restrict__ hdst = hbuf + ((t + 1) & 3) * HSLOT;

    // ---- poll: lanes 0..3 watch this wave's 4 producer roles ----
    for (;;) {
      int v = ldflag<FAST>(myfp);
      if (__all(v >= t)) break;
      __builtin_amdgcn_s_sleep(1);
    }

    // ---- h loads for this wave's K slice (in-asm waitcnt) ----
    const ushort* hb = hsrc + (long)(m0 + (l15 & 7)) * HDIM + wv * 128 + quad * 8;
    short8 ah0, ah1, ah2, ah3;
    ld_h4<FAST>(hb, ah0, ah1, ah2, ah3);

    f32x4 acc[NT];
    #pragma unroll
    for (int nt = 0; nt < NT; ++nt)
      #pragma unroll
      for (int r = 0; r < 4; ++r) acc[nt][r] = 0.0f;

    #pragma unroll
    for (int nt = 0; nt < NT; ++nt)
      acc[nt] = __builtin_amdgcn_mfma_f32_16x16x32_bf16(ah0, wfrag[0][nt], acc[nt], 0, 0, 0);
    #pragma unroll
    for (int nt = 0; nt < NT; ++nt)
      acc[nt] = __builtin_amdgcn_mfma_f32_16x16x32_bf16(ah1, wfrag[1][nt], acc[nt], 0, 0, 0);
    #pragma unroll
    for (int nt = 0; nt < NT; ++nt)
      acc[nt] = __builtin_amdgcn_mfma_f32_16x16x32_bf16(ah2, wfrag[2][nt], acc[nt], 0, 0, 0);
    #pragma unroll
    for (int nt = 0; nt < NT; ++nt)
      acc[nt] = __builtin_amdgcn_mfma_f32_16x16x32_bf16(ah3, wfrag[3][nt], acc[nt], 0, 0, 0);

    // ---- partials to LDS (rows 0..7 only; m=8 of the 16 MFMA rows valid) ----
    if (quad < 2) {
      #pragma unroll
      for (int nt = 0; nt < NT; ++nt)
        #pragma unroll
        for (int r = 0; r < 4; ++r)
          part[(wv * 16 + quad * 4 + r) * PN + nt * 16 + l15] = acc[nt][r];
    }
    __syncthreads();    // all waves passed polls => all 32 group flags >= t
                        // => ring slot (t+1)&3 (holding h(t-3)) safe to overwrite

    // ---- reduce 8 partials, LSTM cell (threads 0..255) ----
    ushort h16 = 0;
    if (tid < 256) {
      float gi = bi + xi, gf = bf_ + xf, gg = bg + xg, go = bo + xo;
      #pragma unroll
      for (int w = 0; w < 8; ++w) {
        const float* pw = part + (w * 16 + em) * PN;
        gi += pw[0 * 32 + uu];
        gf += pw[1 * 32 + uu];
        gg += pw[2 * 32 + uu];
        go += pw[3 * 32 + uu];
      }
      const float si = fast_sigmoid(gi);
      const float sf = fast_sigmoid(gf);
      const float tg = fast_tanh(gg);
      const float so = fast_sigmoid(go);
      cst = sf * cst + si * tg;
      const float h = so * fast_tanh(cst);
      h16 = f2bf(h);
      if constexpr (FAST)
        hdst[(long)(m0 + em) * HDIM + j0u + uu] = h16;      // L2-local (XCD)
      else
        st_h_sys(hdst + (long)(m0 + em) * HDIM + j0u + uu, h16);  // IF
    }

    // ---- publish: own h stores complete before flag store ----
    vm_drain();
    __syncthreads();
    if (tid == 0) stflag<FAST>(fmine, t + 1);   // monotonic, no ABA

    // ---- off-critical-path work after publish ----
    if (tid < 256) {
      if (t >= ILEN)
        hs_bf[((long)(m0 + em) * TLEN + (t - ILEN)) * HDIM + j0u + uu] = h16;
      if (t + 1 < ILEN) {
        const half_t* xq = xgp + (long)(t + 1) * (4 * HDIM);
        xi = (float)xq[0 * HDIM]; xf = (float)xq[1 * HDIM];
        xg = (float)xq[2 * HDIM]; xo = (float)xq[3 * HDIM];
      } else {
        xi = xf = xg = xo = 0.0f;               // padded steps: bias only
      }
    }
  }
}

__global__ __launch_bounds__(NTHR, 2) void lstm_kernel(
    const ushort* __restrict__ whh_sw, const half_t* __restrict__ xproj,
    const float* __restrict__ bias,
    ushort* __restrict__ hbuf, ushort* __restrict__ hs_bf,
    int* __restrict__ flags, int* __restrict__ hand)
{
  // ---- group XCD census: fast path only if all 32 blocks share one XCD ----
  int xcd = 0;
  asm volatile("s_getreg_b32 %0, hwreg(HW_REG_XCC_ID)" : "=s"(xcd));
  const int g = blockIdx.x & 7;
  if (threadIdx.x == 0) {
    __hip_atomic_fetch_or(&hand[g * 8], 1 << (xcd & 7),
                          __ATOMIC_RELAXED, __HIP_MEMORY_SCOPE_SYSTEM);
    __hip_atomic_fetch_add(&hand[64 + g * 8], 1,
                           __ATOMIC_RELAXED, __HIP_MEMORY_SCOPE_SYSTEM);
  }
  while (__hip_atomic_load(&hand[64 + g * 8], __ATOMIC_RELAXED,
                           __HIP_MEMORY_SCOPE_SYSTEM) < GBLK)
    __builtin_amdgcn_s_sleep(2);
  const bool fast =
      __popc(__hip_atomic_load(&hand[g * 8], __ATOMIC_RELAXED,
                               __HIP_MEMORY_SCOPE_SYSTEM)) == 1;

  if (fast) lstm_body<true >(whh_sw, xproj, bias, hbuf, hs_bf, flags);
  else      lstm_body<false>(whh_sw, xproj, bias, hbuf, hs_bf, flags);
}

// ---------------- classifier: sigmoid(hs @ clf_w^T + clf_b) ----------------
__global__ __launch_bounds__(256, 1) void clf_kernel(
    const ushort* __restrict__ hs_bf, const ushort* __restrict__ clfw_bf,
    const float* __restrict__ clf_b, float* __restrict__ out)
{
  const int tid = threadIdx.x;
  const int wv = tid >> 6, lane = tid & 63, l15 = lane & 15, quad = lane >> 4;
  const int m0 = blockIdx.x * 64 + wv * 16;   // rows = (b, tt) pairs, 4096 total

  f32x4 acc[8];
  #pragma unroll
  for (int nt = 0; nt < 8; ++nt)
    #pragma unroll
    for (int r = 0; r < 4; ++r) acc[nt][r] = 0.0f;

  for (int kc = 0; kc < HDIM / 32; ++kc) {
    const int k = kc * 32 + quad * 8;
    short8 a = *(const short8*)(hs_bf + (long)(m0 + l15) * HDIM + k);
    #pragma unroll
    for (int nt = 0; nt < 8; ++nt) {
      short8 b = *(const short8*)(clfw_bf + (long)(nt * 16 + l15) * HDIM + k);
      acc[nt] = __builtin_amdgcn_mfma_f32_16x16x32_bf16(a, b, acc[nt], 0, 0, 0);
    }
  }
  #pragma unroll
  for (int nt = 0; nt < 8; ++nt) {
    const int n = nt * 16 + l15;
    const float bn = clf_b[n];
    #pragma unroll
    for (int r = 0; r < 4; ++r) {
      const int m = m0 + quad * 4 + r;
      out[(long)m * ODIM + n] = fast_sigmoid(acc[nt][r] + bn);
    }
  }
}

// ---------------- launch ----------------
extern "C" void kernel_launch(void* const* d_in, const int* in_sizes, int n_in,
                              void* d_out, int out_size, void* d_ws, size_t ws_size,
                              hipStream_t stream) {
  const float* inp   = (const float*)d_in[0];
  // d_in[1] = tlen scalar (fixed = 64 for this problem)
  const float* w_ih  = (const float*)d_in[2];
  const float* w_hh  = (const float*)d_in[3];
  const float* bias  = (const float*)d_in[4];
  const float* clf_w = (const float*)d_in[5];
  const float* clf_b = (const float*)d_in[6];
  float* out = (float*)d_out;

  // ws layout (bytes): total ~172.8 MB
  char* ws = (char*)d_ws;
  ushort* inp_bf  = (ushort*)(ws + 0);          // 16,777,216
  ushort* wih_bf  = (ushort*)(ws + 16777216);   //  4,194,304
  ushort* whh_sw  = (ushort*)(ws + 20971520);   //  8,388,608 (swizzled w_hh)
  ushort* clfw_bf = (ushort*)(ws + 29360128);   //    262,144
  ushort* hbuf    = (ushort*)(ws + 29622272);   //    524,288 (4-slot h ring)
  ushort* hs_bf   = (ushort*)(ws + 30146560);   //  8,388,608 (last-64-step h)
  int*    bar     = (int*)   (ws + 38535168);   //     32,768 (per-block flags)
  int*    hand    = (int*)   (ws + 38567936);   //      1,024 (XCD census)
  half_t* xproj   = (half_t*)(ws + 38568960);   // 134,217,728 (fp16 x-projection)

  prep_kernel<<<4096, 256, 0, stream>>>(inp, clf_w, w_ih, w_hh,
                                        inp_bf, clfw_bf, wih_bf, whh_sw,
                                        hbuf, bar, hand);
  xproj_kernel<<<8192, 256, 0, stream>>>(inp_bf, wih_bf, xproj);
  lstm_kernel<<<NBLK, NTHR, 8 * 16 * PN * 4, stream>>>(whh_sw, xproj, bias,
                                                       hbuf, hs_bf, bar, hand);
  clf_kernel<<<64, 256, 0, stream>>>(hs_bf, clfw_bf, clf_b, out);
}